// Round 14
// baseline (140.789 us; speedup 1.0000x reference)
//
#include <hip/hip_runtime.h>

#define B_  8
#define TE_ 256
#define TD_ 128
#define HE_ 512

typedef __attribute__((ext_vector_type(8))) short short8v;
typedef __attribute__((ext_vector_type(4))) float f32x4;

// wave64 sum via DPP (VALU, no LDS): result valid in lane 63 only.
__device__ __forceinline__ float wave_red_add(float s) {
#define DPPADD(CTRL) \
  s += __int_as_float(__builtin_amdgcn_update_dpp(0, __float_as_int(s), CTRL, 0xf, 0xf, true))
  DPPADD(0x111);  // row_shr:1
  DPPADD(0x112);  // row_shr:2
  DPPADD(0x114);  // row_shr:4
  DPPADD(0x118);  // row_shr:8  -> lane15 of each row holds row sum
  DPPADD(0x142);  // row_bcast:15
  DPPADD(0x143);  // row_bcast:31 -> lane 63 = total
#undef DPPADD
  return s;
}

// ---- gemm_fused: Cws[3072,512] = [enc;dec] @ (Wa|Ua), trunc-split 3-term bf16 ----
// (R11/R13 config; launched TWICE this round as an idempotent timing probe.)
__global__ __launch_bounds__(512) void gemm_fused(
    const float* __restrict__ enc, const float* __restrict__ dec,
    const float* __restrict__ Wa, const float* __restrict__ Ua,
    float* __restrict__ C) {
  __shared__ short BT[2][32][512];    // 64 KB
  const int bid = blockIdx.x;
  const int mt = bid % 24, nt = bid / 24;
  const int m0 = mt * 128, n0 = nt * 32;
  const float* Bsrc = (mt < 16) ? Wa : Ua;
  const float* Asrc = (mt < 16) ? enc + (size_t)m0 * 512
                                : dec + (size_t)(m0 - 2048) * 512;
  const int tid = threadIdx.x;
  {
    const int kp = tid >> 3;          // 0..63
    const int c4 = (tid & 7) * 4;
    for (int p = 0; p < 4; ++p) {
      const int k = 2 * kp + p * 128;              // even
      float4 v0 = *(const float4*)(Bsrc + (size_t)k * 512 + n0 + c4);
      float4 v1 = *(const float4*)(Bsrc + (size_t)(k + 1) * 512 + n0 + c4);
      const float a0[4] = {v0.x, v0.y, v0.z, v0.w};
      const float a1[4] = {v1.x, v1.y, v1.z, v1.w};
      const int kc = k >> 3, klo = k & 7;
#pragma unroll
      for (int q = 0; q < 4; ++q) {
        const int n = c4 + q;
        unsigned u0 = __float_as_uint(a0[q]);
        unsigned u1 = __float_as_uint(a1[q]);
        unsigned hi32 = __builtin_amdgcn_perm(u1, u0, 0x07060302);
        float l0 = a0[q] - __uint_as_float(u0 & 0xffff0000u);
        float l1 = a1[q] - __uint_as_float(u1 & 0xffff0000u);
        unsigned lo32 = __builtin_amdgcn_perm(__float_as_uint(l1), __float_as_uint(l0), 0x07060302);
        const int slot = (kc & ~7) | ((kc ^ n) & 7);
        *(unsigned*)&BT[0][n][slot * 8 + klo] = hi32;
        *(unsigned*)&BT[1][n][slot * 8 + klo] = lo32;
      }
    }
  }
  __syncthreads();
  const int w = tid >> 6, lane = tid & 63;
  const int fm = lane & 15, fc = lane >> 4;
  const float* Ap = Asrc + (size_t)(w * 16 + fm) * 512 + fc * 8;
  f32x4 acc0 = {}, acc1 = {};
  float4 pfa[2], pfb[2];
  pfa[0] = *(const float4*)(Ap);
  pfb[0] = *(const float4*)(Ap + 4);
  pfa[1] = *(const float4*)(Ap + 32);
  pfb[1] = *(const float4*)(Ap + 36);
  for (int it = 0; it < 16; ++it) {
    const float4 fa = pfa[it & 1];
    const float4 fb = pfb[it & 1];
    if (it < 14) {
      pfa[it & 1] = *(const float4*)(Ap + (it + 2) * 32);
      pfb[it & 1] = *(const float4*)(Ap + (it + 2) * 32 + 4);
    }
    const float af[8] = {fa.x, fa.y, fa.z, fa.w, fb.x, fb.y, fb.z, fb.w};
    union { unsigned u[4]; short8v s; } ahu, alu;
#pragma unroll
    for (int e = 0; e < 4; ++e) {
      unsigned u0 = __float_as_uint(af[2 * e]);
      unsigned u1 = __float_as_uint(af[2 * e + 1]);
      ahu.u[e] = __builtin_amdgcn_perm(u1, u0, 0x07060302);
      float l0 = af[2 * e]     - __uint_as_float(u0 & 0xffff0000u);
      float l1 = af[2 * e + 1] - __uint_as_float(u1 & 0xffff0000u);
      alu.u[e] = __builtin_amdgcn_perm(__float_as_uint(l1), __float_as_uint(l0), 0x07060302);
    }
    const short8v ah = ahu.s, al = alu.s;
    const int kc = it * 4 + fc;
    const int base = kc & ~7;
    const int s0 = (base | ((kc ^ fm) & 7)) * 8;
    const int s1 = (base | ((kc ^ (16 + fm)) & 7)) * 8;
    short8v bh0 = *(const short8v*)&BT[0][fm][s0];
    short8v bl0 = *(const short8v*)&BT[1][fm][s0];
    short8v bh1 = *(const short8v*)&BT[0][16 + fm][s1];
    short8v bl1 = *(const short8v*)&BT[1][16 + fm][s1];
    acc0 = __builtin_amdgcn_mfma_f32_16x16x32_bf16(ah, bh0, acc0, 0, 0, 0);
    acc1 = __builtin_amdgcn_mfma_f32_16x16x32_bf16(ah, bh1, acc1, 0, 0, 0);
    acc0 = __builtin_amdgcn_mfma_f32_16x16x32_bf16(ah, bl0, acc0, 0, 0, 0);
    acc1 = __builtin_amdgcn_mfma_f32_16x16x32_bf16(ah, bl1, acc1, 0, 0, 0);
    acc0 = __builtin_amdgcn_mfma_f32_16x16x32_bf16(al, bh0, acc0, 0, 0, 0);
    acc1 = __builtin_amdgcn_mfma_f32_16x16x32_bf16(al, bh1, acc1, 0, 0, 0);
  }
  const int row = m0 + w * 16 + fc * 4;
  float* Cp = C + (size_t)row * 512 + n0 + fm;
#pragma unroll
  for (int r = 0; r < 4; ++r) Cp[(size_t)r * 512] = acc0[r];
#pragma unroll
  for (int r = 0; r < 4; ++r) Cp[(size_t)r * 512 + 16] = acc1[r];
}

// ---- attn_fused: 512 blocks x 1024 thr, 2-d tiles, DPP, depth-2 prefetch ----
#define C2 2.8853900817779268f   // 2*log2(e)
__global__ __launch_bounds__(1024) void attn_fused(
    const float* __restrict__ Ws, const float* __restrict__ Uh,
    const float* __restrict__ Va, const float* __restrict__ enc,
    float* __restrict__ c_out, float* __restrict__ e_out) {
  __shared__ float sUh[2][HE_];
  __shared__ float sV[HE_];
  __shared__ float sE[2][TE_];
  __shared__ float sRed[8];
  __shared__ float sNorm[2];
  const int tid = threadIdx.x;
  const int b  = blockIdx.x & 7;          // XCD-aligned b partition
  const int d0 = (blockIdx.x >> 3) * 2;   // 64 d-tiles x 8 b = 512 blocks
  if (tid < 256)
    ((float4*)sUh)[tid] = ((const float4*)(Uh + (size_t)(b * TD_ + d0) * HE_))[tid];
  else if (tid < 384)
    ((float4*)sV)[tid - 256] = ((const float4*)Va)[tid - 256];
  __syncthreads();
  const int lane = tid & 63, w = tid >> 6;   // 16 waves
  const int tb = w * 16;                     // 16 t per wave, both d's
  const int h0 = lane * 8;
  float eU[2][8], vv2[8], sumv = 0.f;
#pragma unroll
  for (int j = 0; j < 8; ++j) {
    const float vj = sV[h0 + j];
    sumv += vj;
    vv2[j] = 2.0f * vj;
    eU[0][j] = __builtin_amdgcn_exp2f(C2 * sUh[0][h0 + j]);
    eU[1][j] = __builtin_amdgcn_exp2f(C2 * sUh[1][h0 + j]);
  }
  const float* pw = Ws + ((size_t)b * TE_ + tb) * HE_ + h0;
  // depth-2 prefetch pipeline: a = row t, bb = row t+1, fetch row t+2 in-loop.
  // Worst prefetch row = b*256 + tb + 17 <= 2049 < 3072 -> lands in Uh, safe.
  float4 a0 = *(const float4*)(pw);
  float4 a1 = *(const float4*)(pw + 4);
  float4 b0 = *(const float4*)(pw + HE_);
  float4 b1 = *(const float4*)(pw + HE_ + 4);
  float s0, s1;
#define TELT2(X, J) { \
    float EW = __builtin_amdgcn_exp2f(C2 * (X)); \
    float E0 = EW * eU[0][J], E1 = EW * eU[1][J]; \
    float r0 = __builtin_amdgcn_rcpf(E0 + 1.0f); \
    float r1 = __builtin_amdgcn_rcpf(E1 + 1.0f); \
    s0 = fmaf(-vv2[J], r0, s0); s1 = fmaf(-vv2[J], r1, s1); }
  for (int ti = 0; ti < 16; ++ti) {
    const float* p2 = pw + 2 * HE_;
    float4 n0 = *(const float4*)(p2);
    float4 n1 = *(const float4*)(p2 + 4);
    s0 = s1 = sumv;
    TELT2(a0.x, 0) TELT2(a0.y, 1) TELT2(a0.z, 2) TELT2(a0.w, 3)
    TELT2(a1.x, 4) TELT2(a1.y, 5) TELT2(a1.z, 6) TELT2(a1.w, 7)
    s0 = wave_red_add(s0);
    s1 = wave_red_add(s1);
    if (lane == 63) {
      sE[0][tb + ti] = s0;
      sE[1][tb + ti] = s1;
    }
    a0 = b0; a1 = b1;
    b0 = n0; b1 = n1;
    pw += HE_;
  }
  __syncthreads();
  // softmax (no max-subtraction: |logit| <= sum|V| ~ 21, exp safe in fp32)
  if (tid < 512) {
    const int dA = tid >> 8, t = tid & 255;
    const float ex = __expf(sE[dA][t]);
    float sum = wave_red_add(ex);
    if (lane == 63) sRed[w] = sum;           // waves 0..3 -> d0, 4..7 -> d1
    __syncthreads();
    if (tid < 2)
      sNorm[tid] = 1.0f / (sRed[tid * 4] + sRed[tid * 4 + 1] + sRed[tid * 4 + 2] + sRed[tid * 4 + 3]);
    __syncthreads();
    const float wgt = ex * sNorm[dA];
    sE[dA][t] = wgt;
    e_out[(size_t)(b * TD_ + d0 + dA) * TE_ + t] = wgt;
  } else {
    __syncthreads();
    __syncthreads();
  }
  __syncthreads();
  // phase 3: tid<512 -> d0, tid>=512 -> d0+1; h = tid & 511; unroll 8
  const int h = tid & 511;
  const int dd = tid >> 9;
  float acc = 0.f;
  const float* ep = enc + (size_t)b * TE_ * HE_ + h;
  const float* ew = sE[dd];
#pragma unroll 8
  for (int tt = 0; tt < TE_; ++tt)
    acc = fmaf(ew[tt], ep[(size_t)tt * HE_], acc);
  c_out[(size_t)(b * TD_ + d0 + dd) * HE_ + h] = acc;
}

extern "C" void kernel_launch(void* const* d_in, const int* in_sizes, int n_in,
                              void* d_out, int out_size, void* d_ws, size_t ws_size,
                              hipStream_t stream) {
  const float* enc = (const float*)d_in[0];   // [8,256,512]
  const float* dec = (const float*)d_in[1];   // [8,128,512]
  const float* Wa  = (const float*)d_in[2];   // [512,512]
  const float* Ua  = (const float*)d_in[3];   // [512,512]
  const float* Va  = (const float*)d_in[4];   // [512,1]
  float* c_out = (float*)d_out;
  float* e_out = c_out + (size_t)B_ * TD_ * HE_;
  float* Cws = (float*)d_ws;                   // [3072,512] fp32 = 6 MB
  const float* Ws = Cws;                       // rows 0..2047
  const float* Uh = Cws + (size_t)2048 * 512;  // rows 2048..3071
  // PROBE: gemm launched twice (idempotent). Delta vs R13 isolates gemm cost.
  gemm_fused<<<384, 512, 0, stream>>>(enc, dec, Wa, Ua, Cws);
  gemm_fused<<<384, 512, 0, stream>>>(enc, dec, Wa, Ua, Cws);
  attn_fused<<<512, 1024, 0, stream>>>(Ws, Uh, Va, enc, c_out, e_out);
}

// Round 15
// 117.067 us; speedup vs baseline: 1.2026x; 1.2026x over previous
//
#include <hip/hip_runtime.h>

#define B_  8
#define TE_ 256
#define TD_ 128
#define HE_ 512

typedef __attribute__((ext_vector_type(8))) short short8v;
typedef __attribute__((ext_vector_type(4))) float f32x4;

#define C2 2.8853900817779268f   // 2*log2(e)

// wave64 sum via DPP (VALU, no LDS): result valid in lane 63 only.
__device__ __forceinline__ float wave_red_add(float s) {
#define DPPADD(CTRL) \
  s += __int_as_float(__builtin_amdgcn_update_dpp(0, __float_as_int(s), CTRL, 0xf, 0xf, true))
  DPPADD(0x111);  // row_shr:1
  DPPADD(0x112);  // row_shr:2
  DPPADD(0x114);  // row_shr:4
  DPPADD(0x118);  // row_shr:8  -> lane15 of each row holds row sum
  DPPADD(0x142);  // row_bcast:15
  DPPADD(0x143);  // row_bcast:31 -> lane 63 = total
#undef DPPADD
  return s;
}

// ---- gemm_fused: Cws[3072,512] = [enc;dec] @ (Wa|Ua), trunc-split 3-term bf16 ----
// R11/R13 config. NEW: epilogue stores EW = exp2(C2*Ws) for enc rows (0..2047),
// hoisting the per-(b,t,h) exp out of attn (it was recomputed by 64 d-blocks).
__global__ __launch_bounds__(512) void gemm_fused(
    const float* __restrict__ enc, const float* __restrict__ dec,
    const float* __restrict__ Wa, const float* __restrict__ Ua,
    float* __restrict__ C) {
  __shared__ short BT[2][32][512];    // 64 KB
  const int bid = blockIdx.x;
  const int mt = bid % 24, nt = bid / 24;
  const int m0 = mt * 128, n0 = nt * 32;
  const bool isenc = (mt < 16);
  const float* Bsrc = isenc ? Wa : Ua;
  const float* Asrc = isenc ? enc + (size_t)m0 * 512
                            : dec + (size_t)(m0 - 2048) * 512;
  const int tid = threadIdx.x;
  {
    const int kp = tid >> 3;          // 0..63
    const int c4 = (tid & 7) * 4;
    for (int p = 0; p < 4; ++p) {
      const int k = 2 * kp + p * 128;              // even
      float4 v0 = *(const float4*)(Bsrc + (size_t)k * 512 + n0 + c4);
      float4 v1 = *(const float4*)(Bsrc + (size_t)(k + 1) * 512 + n0 + c4);
      const float a0[4] = {v0.x, v0.y, v0.z, v0.w};
      const float a1[4] = {v1.x, v1.y, v1.z, v1.w};
      const int kc = k >> 3, klo = k & 7;
#pragma unroll
      for (int q = 0; q < 4; ++q) {
        const int n = c4 + q;
        unsigned u0 = __float_as_uint(a0[q]);
        unsigned u1 = __float_as_uint(a1[q]);
        unsigned hi32 = __builtin_amdgcn_perm(u1, u0, 0x07060302);
        float l0 = a0[q] - __uint_as_float(u0 & 0xffff0000u);
        float l1 = a1[q] - __uint_as_float(u1 & 0xffff0000u);
        unsigned lo32 = __builtin_amdgcn_perm(__float_as_uint(l1), __float_as_uint(l0), 0x07060302);
        const int slot = (kc & ~7) | ((kc ^ n) & 7);
        *(unsigned*)&BT[0][n][slot * 8 + klo] = hi32;
        *(unsigned*)&BT[1][n][slot * 8 + klo] = lo32;
      }
    }
  }
  __syncthreads();
  const int w = tid >> 6, lane = tid & 63;
  const int fm = lane & 15, fc = lane >> 4;
  const float* Ap = Asrc + (size_t)(w * 16 + fm) * 512 + fc * 8;
  f32x4 acc0 = {}, acc1 = {};
  float4 pfa[2], pfb[2];
  pfa[0] = *(const float4*)(Ap);
  pfb[0] = *(const float4*)(Ap + 4);
  pfa[1] = *(const float4*)(Ap + 32);
  pfb[1] = *(const float4*)(Ap + 36);
  for (int it = 0; it < 16; ++it) {
    const float4 fa = pfa[it & 1];
    const float4 fb = pfb[it & 1];
    if (it < 14) {
      pfa[it & 1] = *(const float4*)(Ap + (it + 2) * 32);
      pfb[it & 1] = *(const float4*)(Ap + (it + 2) * 32 + 4);
    }
    const float af[8] = {fa.x, fa.y, fa.z, fa.w, fb.x, fb.y, fb.z, fb.w};
    union { unsigned u[4]; short8v s; } ahu, alu;
#pragma unroll
    for (int e = 0; e < 4; ++e) {
      unsigned u0 = __float_as_uint(af[2 * e]);
      unsigned u1 = __float_as_uint(af[2 * e + 1]);
      ahu.u[e] = __builtin_amdgcn_perm(u1, u0, 0x07060302);
      float l0 = af[2 * e]     - __uint_as_float(u0 & 0xffff0000u);
      float l1 = af[2 * e + 1] - __uint_as_float(u1 & 0xffff0000u);
      alu.u[e] = __builtin_amdgcn_perm(__float_as_uint(l1), __float_as_uint(l0), 0x07060302);
    }
    const short8v ah = ahu.s, al = alu.s;
    const int kc = it * 4 + fc;
    const int base = kc & ~7;
    const int s0 = (base | ((kc ^ fm) & 7)) * 8;
    const int s1 = (base | ((kc ^ (16 + fm)) & 7)) * 8;
    short8v bh0 = *(const short8v*)&BT[0][fm][s0];
    short8v bl0 = *(const short8v*)&BT[1][fm][s0];
    short8v bh1 = *(const short8v*)&BT[0][16 + fm][s1];
    short8v bl1 = *(const short8v*)&BT[1][16 + fm][s1];
    acc0 = __builtin_amdgcn_mfma_f32_16x16x32_bf16(ah, bh0, acc0, 0, 0, 0);
    acc1 = __builtin_amdgcn_mfma_f32_16x16x32_bf16(ah, bh1, acc1, 0, 0, 0);
    acc0 = __builtin_amdgcn_mfma_f32_16x16x32_bf16(ah, bl0, acc0, 0, 0, 0);
    acc1 = __builtin_amdgcn_mfma_f32_16x16x32_bf16(ah, bl1, acc1, 0, 0, 0);
    acc0 = __builtin_amdgcn_mfma_f32_16x16x32_bf16(al, bh0, acc0, 0, 0, 0);
    acc1 = __builtin_amdgcn_mfma_f32_16x16x32_bf16(al, bh1, acc1, 0, 0, 0);
  }
  const int row = m0 + w * 16 + fc * 4;
  float* Cp = C + (size_t)row * 512 + n0 + fm;
  if (isenc) {
#pragma unroll
    for (int r = 0; r < 4; ++r)
      Cp[(size_t)r * 512] = __builtin_amdgcn_exp2f(C2 * acc0[r]);
#pragma unroll
    for (int r = 0; r < 4; ++r)
      Cp[(size_t)r * 512 + 16] = __builtin_amdgcn_exp2f(C2 * acc1[r]);
  } else {
#pragma unroll
    for (int r = 0; r < 4; ++r) Cp[(size_t)r * 512] = acc0[r];
#pragma unroll
    for (int r = 0; r < 4; ++r) Cp[(size_t)r * 512 + 16] = acc1[r];
  }
}

// ---- attn_fused: 512 blocks x 1024 thr, 2-d tiles, DPP, EW-precomputed ----
// EWs holds 2^(C2*Ws); tanh contribution = v - 2v*rcp(EW*eU + 1).
__global__ __launch_bounds__(1024) void attn_fused(
    const float* __restrict__ EWs, const float* __restrict__ Uh,
    const float* __restrict__ Va, const float* __restrict__ enc,
    float* __restrict__ c_out, float* __restrict__ e_out) {
  __shared__ float sUh[2][HE_];
  __shared__ float sV[HE_];
  __shared__ float sE[2][TE_];
  __shared__ float sRed[8];
  __shared__ float sNorm[2];
  const int tid = threadIdx.x;
  const int b  = blockIdx.x & 7;          // XCD-aligned b partition
  const int d0 = (blockIdx.x >> 3) * 2;   // 64 d-tiles x 8 b = 512 blocks
  if (tid < 256)
    ((float4*)sUh)[tid] = ((const float4*)(Uh + (size_t)(b * TD_ + d0) * HE_))[tid];
  else if (tid < 384)
    ((float4*)sV)[tid - 256] = ((const float4*)Va)[tid - 256];
  __syncthreads();
  const int lane = tid & 63, w = tid >> 6;   // 16 waves
  const int tb = w * 16;                     // 16 t per wave, both d's
  const int h0 = lane * 8;
  float eU[2][8], vv2[8], sumv = 0.f;
#pragma unroll
  for (int j = 0; j < 8; ++j) {
    const float vj = sV[h0 + j];
    sumv += vj;
    vv2[j] = 2.0f * vj;
    eU[0][j] = __builtin_amdgcn_exp2f(C2 * sUh[0][h0 + j]);
    eU[1][j] = __builtin_amdgcn_exp2f(C2 * sUh[1][h0 + j]);
  }
  const float* pw = EWs + ((size_t)b * TE_ + tb) * HE_ + h0;
  float4 a0 = *(const float4*)(pw);
  float4 a1 = *(const float4*)(pw + 4);
  float s0, s1;
#define TELT2(X, J) { \
    float E0 = (X) * eU[0][J]; \
    float E1 = (X) * eU[1][J]; \
    float r0 = __builtin_amdgcn_rcpf(E0 + 1.0f); \
    float r1 = __builtin_amdgcn_rcpf(E1 + 1.0f); \
    s0 = fmaf(-vv2[J], r0, s0); s1 = fmaf(-vv2[J], r1, s1); }
  for (int ti = 0; ti < 16; ++ti) {
    const float* pn = pw + HE_;
    float4 n0 = *(const float4*)(pn);       // depth-1 prefetch (R13 best)
    float4 n1 = *(const float4*)(pn + 4);
    s0 = s1 = sumv;
    TELT2(a0.x, 0) TELT2(a0.y, 1) TELT2(a0.z, 2) TELT2(a0.w, 3)
    TELT2(a1.x, 4) TELT2(a1.y, 5) TELT2(a1.z, 6) TELT2(a1.w, 7)
    s0 = wave_red_add(s0);
    s1 = wave_red_add(s1);
    if (lane == 63) {
      sE[0][tb + ti] = s0;
      sE[1][tb + ti] = s1;
    }
    a0 = n0; a1 = n1;
    pw = pn;
  }
  __syncthreads();
  // softmax (no max-subtraction: |logit| <= sum|V| ~ 21, exp safe in fp32)
  if (tid < 512) {
    const int dA = tid >> 8, t = tid & 255;
    const float ex = __expf(sE[dA][t]);
    float sum = wave_red_add(ex);
    if (lane == 63) sRed[w] = sum;           // waves 0..3 -> d0, 4..7 -> d1
    __syncthreads();
    if (tid < 2)
      sNorm[tid] = 1.0f / (sRed[tid * 4] + sRed[tid * 4 + 1] + sRed[tid * 4 + 2] + sRed[tid * 4 + 3]);
    __syncthreads();
    const float wgt = ex * sNorm[dA];
    sE[dA][t] = wgt;
    e_out[(size_t)(b * TD_ + d0 + dA) * TE_ + t] = wgt;
  } else {
    __syncthreads();
    __syncthreads();
  }
  __syncthreads();
  // phase 3: tid<512 -> d0, tid>=512 -> d0+1; h = tid & 511; unroll 8
  const int h = tid & 511;
  const int dd = tid >> 9;
  float acc = 0.f;
  const float* ep = enc + (size_t)b * TE_ * HE_ + h;
  const float* ew = sE[dd];
#pragma unroll 8
  for (int tt = 0; tt < TE_; ++tt)
    acc = fmaf(ew[tt], ep[(size_t)tt * HE_], acc);
  c_out[(size_t)(b * TD_ + d0 + dd) * HE_ + h] = acc;
}

extern "C" void kernel_launch(void* const* d_in, const int* in_sizes, int n_in,
                              void* d_out, int out_size, void* d_ws, size_t ws_size,
                              hipStream_t stream) {
  const float* enc = (const float*)d_in[0];   // [8,256,512]
  const float* dec = (const float*)d_in[1];   // [8,128,512]
  const float* Wa  = (const float*)d_in[2];   // [512,512]
  const float* Ua  = (const float*)d_in[3];   // [512,512]
  const float* Va  = (const float*)d_in[4];   // [512,1]
  float* c_out = (float*)d_out;
  float* e_out = c_out + (size_t)B_ * TD_ * HE_;
  float* Cws = (float*)d_ws;                   // [3072,512] fp32 = 6 MB
  const float* EWs = Cws;                      // rows 0..2047: exp2(C2*Ws)
  const float* Uh  = Cws + (size_t)2048 * 512; // rows 2048..3071: raw Uh
  gemm_fused<<<384, 512, 0, stream>>>(enc, dec, Wa, Ua, Cws);
  attn_fused<<<512, 1024, 0, stream>>>(EWs, Uh, Va, enc, c_out, e_out);
}